// Round 7
// baseline (328.739 us; speedup 1.0000x reference)
//
#include <hip/hip_runtime.h>

// Trilinear interpolation: input [16][128][128][128] fp32, coords [N][3] in [-1,1],
// out [16][N] fp32.
//
// R10: R9b + NON-TEMPORAL ws stores in the transpose.
// Rationale from counters: interp FETCH ~259 MB == full demand -> LLC retains
// none of ws anyway, so cache-allocating ws stores only churn the LLC (and
// displace resident input lines: input is iteration-invariant, transpose FETCH
// 65 MB < 134 MB input proves partial residency). NT-stream the 131 MB ws write.
// Layout unchanged: 64 B pair line s = {16ch bf16 @ z, 16ch bf16 @ z+1 clamped};
// interp reads exactly 4 aligned 64 B lines/pt (256 B payload floor) at the
// measured ~3.6 TB/s random-access per-byte wall (R7: bigger transactions
// don't lift it; R4: sorting loses).

#define GD   128
#define NCH  16
constexpr int VOX = GD * GD * GD;

typedef float    vf4 __attribute__((ext_vector_type(4)));
typedef unsigned uv4 __attribute__((ext_vector_type(4)));

__device__ __forceinline__ unsigned short f2bf_rne(float f) {
    unsigned u = __builtin_bit_cast(unsigned, f);
    u = u + 0x7fffu + ((u >> 16) & 1u);   // round-nearest-even
    return (unsigned short)(u >> 16);
}

// ---------- transpose: dwordx4 NT reads, LDS staging, NT coalesced line output ----------
__global__ __launch_bounds__(256) void transpose_pair_nt_k(const float* __restrict__ in,
                                                           unsigned* __restrict__ ws) {
    __shared__ unsigned lds[1024 * 8];   // 32 KB: 1024 voxels x 16ch bf16
    int t  = threadIdx.x;
    int s0 = blockIdx.x * 1024;          // block owns voxels [s0, s0+1024) = 8 z-columns

    // 16 batched NT dwordx4 loads: channel c, voxels s0+4t .. s0+4t+3
    vf4 a[NCH];
#pragma unroll
    for (int c = 0; c < NCH; ++c)
        a[c] = __builtin_nontemporal_load(
            (const vf4*)(in + (size_t)c * VOX + s0) + t);

    // pack: voxel j (of this thread's 4) -> 8 uints of 16 bf16 channels
#pragma unroll
    for (int j = 0; j < 4; ++j) {
        unsigned* dst = lds + (4 * t + j) * 8;
#pragma unroll
        for (int k = 0; k < 8; ++k) {
            dst[k] = (unsigned)f2bf_rne(a[2 * k][j])
                   | ((unsigned)f2bf_rne(a[2 * k + 1][j]) << 16);
        }
    }

    __syncthreads();

    // emit block's 4096 output uint4s (64 KB): lane-contiguous NT stores.
    // line l: slots {lo(z), hi(z), lo(z+1 clamped), hi(z+1 clamped)}
    const uv4* l4 = (const uv4*)lds;           // local voxel v = uv4s {2v, 2v+1}
    uv4* o = (uv4*)ws + (size_t)s0 * 4;
#pragma unroll
    for (int g = 0; g < 16; ++g) {
        int idx  = t + 256 * g;                // 0..4095
        int line = idx >> 2;                   // 0..1023 within block
        int col  = line >> 7;                  // which z-column (0..7)
        int z    = line & (GD - 1);
        int slot = idx & 3;
        int vz   = min(z + (slot >> 1), GD - 1);   // slot 2/3 -> z+1, clamped
        __builtin_nontemporal_store(l4[(col * GD + vz) * 2 + (slot & 1)], o + idx);
    }
}

// ---------- interp: 4 corner-lines x 64 B, all 16 loads batched (unchanged control) ----------
__global__ __launch_bounds__(256) void interp_pair_k(const uint4* __restrict__ ws,
                                                     const float* __restrict__ coords,
                                                     float* __restrict__ out, int N) {
    int n = blockIdx.x * 256 + threadIdx.x;
    if (n >= N) return;

    float cx = (coords[3 * n + 0] + 1.0f) * 0.5f * (float)(GD - 1);
    float cy = (coords[3 * n + 1] + 1.0f) * 0.5f * (float)(GD - 1);
    float cz = (coords[3 * n + 2] + 1.0f) * 0.5f * (float)(GD - 1);

    float fx = floorf(cx), fy = floorf(cy), fz = floorf(cz);
    float tx = cx - fx, ty = cy - fy, tz = cz - fz;
    int ix = (int)fx, iy = (int)fy, iz = (int)fz;

    int ix0 = min(max(ix,     0), GD - 1), ix1 = min(max(ix + 1, 0), GD - 1);
    int iy0 = min(max(iy,     0), GD - 1), iy1 = min(max(iy + 1, 0), GD - 1);
    int iz0 = min(max(iz,     0), GD - 1);
    // pair line at iz0 holds z=iz0 and z=min(iz0+1, GD-1) == clamped iz1. exact.

    float wx0 = 1.0f - tx, wx1 = tx;
    float wy0 = 1.0f - ty, wy1 = ty;
    float wz0 = 1.0f - tz, wz1 = tz;

    const uint4* p0 = ws + ((size_t)(ix0 * GD + iy0) * GD + iz0) * 4;
    const uint4* p1 = ws + ((size_t)(ix0 * GD + iy1) * GD + iz0) * 4;
    const uint4* p2 = ws + ((size_t)(ix1 * GD + iy0) * GD + iz0) * 4;
    const uint4* p3 = ws + ((size_t)(ix1 * GD + iy1) * GD + iz0) * 4;

    // batch ALL 16 line-loads up front: maximal MLP per wave
    uint4 q[16];
#pragma unroll
    for (int j = 0; j < 4; ++j) {
        q[0 + j]  = p0[j];
        q[4 + j]  = p1[j];
        q[8 + j]  = p2[j];
        q[12 + j] = p3[j];
    }

    float wxy[4] = { wx0 * wy0, wx0 * wy1, wx1 * wy0, wx1 * wy1 };

    float acc[NCH];
#pragma unroll
    for (int c = 0; c < NCH; ++c) acc[c] = 0.0f;

#pragma unroll
    for (int r = 0; r < 4; ++r) {
        unsigned u0[8] = { q[4 * r + 0].x, q[4 * r + 0].y, q[4 * r + 0].z, q[4 * r + 0].w,
                           q[4 * r + 1].x, q[4 * r + 1].y, q[4 * r + 1].z, q[4 * r + 1].w };
        unsigned u1[8] = { q[4 * r + 2].x, q[4 * r + 2].y, q[4 * r + 2].z, q[4 * r + 2].w,
                           q[4 * r + 3].x, q[4 * r + 3].y, q[4 * r + 3].z, q[4 * r + 3].w };
        float wxyr = wxy[r];
#pragma unroll
        for (int k = 0; k < 8; ++k) {
            float z0lo = __builtin_bit_cast(float, u0[k] << 16);
            float z0hi = __builtin_bit_cast(float, u0[k] & 0xffff0000u);
            float z1lo = __builtin_bit_cast(float, u1[k] << 16);
            float z1hi = __builtin_bit_cast(float, u1[k] & 0xffff0000u);
            acc[2 * k + 0] += wxyr * (wz0 * z0lo + wz1 * z1lo);
            acc[2 * k + 1] += wxyr * (wz0 * z0hi + wz1 * z1hi);
        }
    }

#pragma unroll
    for (int c = 0; c < NCH; ++c)
        __builtin_nontemporal_store(acc[c], out + (size_t)c * N + n);  // never re-read
}

// ---------- fallback: direct gather from native layout (fp32) ----------
__global__ __launch_bounds__(256) void interp_direct_k(const float* __restrict__ in,
                                                       const float* __restrict__ coords,
                                                       float* __restrict__ out, int N) {
    int n = blockIdx.x * 256 + threadIdx.x;
    if (n >= N) return;
    float cx = (coords[3 * n + 0] + 1.0f) * 0.5f * (float)(GD - 1);
    float cy = (coords[3 * n + 1] + 1.0f) * 0.5f * (float)(GD - 1);
    float cz = (coords[3 * n + 2] + 1.0f) * 0.5f * (float)(GD - 1);
    float fx = floorf(cx), fy = floorf(cy), fz = floorf(cz);
    float tx = cx - fx, ty = cy - fy, tz = cz - fz;
    int ix = (int)fx, iy = (int)fy, iz = (int)fz;
    int ix0 = min(max(ix, 0), GD - 1), ix1 = min(max(ix + 1, 0), GD - 1);
    int iy0 = min(max(iy, 0), GD - 1), iy1 = min(max(iy + 1, 0), GD - 1);
    int iz0 = min(max(iz, 0), GD - 1), iz1 = min(max(iz + 1, 0), GD - 1);
    float wx0 = 1.0f - tx, wx1 = tx, wy0 = 1.0f - ty, wy1 = ty, wz0 = 1.0f - tz, wz1 = tz;
    int o000 = (ix0 * GD + iy0) * GD + iz0, o001 = (ix0 * GD + iy0) * GD + iz1;
    int o010 = (ix0 * GD + iy1) * GD + iz0, o011 = (ix0 * GD + iy1) * GD + iz1;
    int o100 = (ix1 * GD + iy0) * GD + iz0, o101 = (ix1 * GD + iy0) * GD + iz1;
    int o110 = (ix1 * GD + iy1) * GD + iz0, o111 = (ix1 * GD + iy1) * GD + iz1;
    float w000 = wx0 * wy0 * wz0, w001 = wx0 * wy0 * wz1;
    float w010 = wx0 * wy1 * wz0, w011 = wx0 * wy1 * wz1;
    float w100 = wx1 * wy0 * wz0, w101 = wx1 * wy0 * wz1;
    float w110 = wx1 * wy1 * wz0, w111 = wx1 * wy1 * wz1;
#pragma unroll
    for (int c = 0; c < NCH; ++c) {
        const float* g = in + (size_t)c * VOX;
        float acc = w000 * g[o000] + w001 * g[o001] + w010 * g[o010] + w011 * g[o011]
                  + w100 * g[o100] + w101 * g[o101] + w110 * g[o110] + w111 * g[o111];
        out[(size_t)c * N + n] = acc;
    }
}

extern "C" void kernel_launch(void* const* d_in, const int* in_sizes, int n_in,
                              void* d_out, int out_size, void* d_ws, size_t ws_size,
                              hipStream_t stream) {
    const float* input  = (const float*)d_in[0];
    const float* coords = (const float*)d_in[1];
    float* out = (float*)d_out;
    int N = in_sizes[1] / 3;  // 1,000,000
    int nb = (N + 255) / 256;

    size_t need = (size_t)VOX * 64;  // 134,217,728 B pair layout
    if (ws_size >= need) {
        transpose_pair_nt_k<<<VOX / 1024, 256, 0, stream>>>(input, (unsigned*)d_ws);
        interp_pair_k<<<nb, 256, 0, stream>>>((const uint4*)d_ws, coords, out, N);
    } else {
        interp_direct_k<<<nb, 256, 0, stream>>>(input, coords, out, N);
    }
}

// Round 8
// 302.382 us; speedup vs baseline: 1.0872x; 1.0872x over previous
//
#include <hip/hip_runtime.h>

// Trilinear interpolation: input [16][128][128][128] fp32, coords [N][3] in [-1,1],
// out [16][N] fp32.
//
// R11: revert R10's NT ws stores (regressed interp 91->117 us: NT-written lines
// degrade the subsequent random-read path). Back to R9b config, with ONE change:
// transpose blocks cover 2048 voxels (8 KB contiguous burst per channel-stream
// per block, 32 concurrent dwordx4 NT loads) to attack the transpose's 2.6 TB/s
// plateau, which persisted across 3 store-side rewrites -> read-burst theory.
// Layout unchanged: 64 B pair line s = {16ch bf16 @ z, 16ch bf16 @ z+1 clamped};
// interp reads 4 aligned 64 B lines/pt (256 B payload floor) at the measured
// ~3.6 TB/s random-access wall (within 3% of floor).

#define GD   128
#define NCH  16
constexpr int VOX = GD * GD * GD;

typedef float vf4 __attribute__((ext_vector_type(4)));

__device__ __forceinline__ unsigned short f2bf_rne(float f) {
    unsigned u = __builtin_bit_cast(unsigned, f);
    u = u + 0x7fffu + ((u >> 16) & 1u);   // round-nearest-even
    return (unsigned short)(u >> 16);
}

// ---------- transpose: 2048-voxel blocks, 8 KB/channel bursts, LDS, coalesced out ----------
__global__ __launch_bounds__(256) void transpose_pair_b2_k(const float* __restrict__ in,
                                                           uint4* __restrict__ ws) {
    __shared__ unsigned lds[2048 * 8];   // 64 KB: 2048 voxels x 16ch bf16
    int t  = threadIdx.x;
    int s0 = blockIdx.x * 2048;          // block owns voxels [s0, s0+2048) = 16 z-columns

    // 32 batched NT dwordx4 loads: 16 channels x 2 sub-rows -> 8 KB burst/channel
    vf4 a[NCH][2];
#pragma unroll
    for (int c = 0; c < NCH; ++c)
#pragma unroll
        for (int r = 0; r < 2; ++r)
            a[c][r] = __builtin_nontemporal_load(
                (const vf4*)(in + (size_t)c * VOX + s0) + (r * 256 + t));

    // pack: sub-row r, voxel j -> local voxel 4*(r*256+t)+j, 8 uints of 16 bf16 ch
#pragma unroll
    for (int r = 0; r < 2; ++r) {
#pragma unroll
        for (int j = 0; j < 4; ++j) {
            unsigned* dst = lds + (size_t)(4 * (r * 256 + t) + j) * 8;
#pragma unroll
            for (int k = 0; k < 8; ++k) {
                dst[k] = (unsigned)f2bf_rne(a[2 * k][r][j])
                       | ((unsigned)f2bf_rne(a[2 * k + 1][r][j]) << 16);
            }
        }
    }

    __syncthreads();

    // emit block's 8192 output uint4s (128 KB): lane-contiguous stores.
    // line l: slots {lo(z), hi(z), lo(z+1 clamped), hi(z+1 clamped)}
    const uint4* l4 = (const uint4*)lds;       // local voxel v = uint4s {2v, 2v+1}
    uint4* o = ws + (size_t)s0 * 4;
#pragma unroll
    for (int g = 0; g < 32; ++g) {
        int idx  = t + 256 * g;                // 0..8191
        int line = idx >> 2;                   // 0..2047 within block
        int col  = line >> 7;                  // which z-column (0..15)
        int z    = line & (GD - 1);
        int slot = idx & 3;
        int vz   = min(z + (slot >> 1), GD - 1);   // slot 2/3 -> z+1, clamped
        o[idx] = l4[(col * GD + vz) * 2 + (slot & 1)];
    }
}

// ---------- interp: 4 corner-lines x 64 B, all 16 loads batched (R9b, unchanged) ----------
__global__ __launch_bounds__(256) void interp_pair_k(const uint4* __restrict__ ws,
                                                     const float* __restrict__ coords,
                                                     float* __restrict__ out, int N) {
    int n = blockIdx.x * 256 + threadIdx.x;
    if (n >= N) return;

    float cx = (coords[3 * n + 0] + 1.0f) * 0.5f * (float)(GD - 1);
    float cy = (coords[3 * n + 1] + 1.0f) * 0.5f * (float)(GD - 1);
    float cz = (coords[3 * n + 2] + 1.0f) * 0.5f * (float)(GD - 1);

    float fx = floorf(cx), fy = floorf(cy), fz = floorf(cz);
    float tx = cx - fx, ty = cy - fy, tz = cz - fz;
    int ix = (int)fx, iy = (int)fy, iz = (int)fz;

    int ix0 = min(max(ix,     0), GD - 1), ix1 = min(max(ix + 1, 0), GD - 1);
    int iy0 = min(max(iy,     0), GD - 1), iy1 = min(max(iy + 1, 0), GD - 1);
    int iz0 = min(max(iz,     0), GD - 1);
    // pair line at iz0 holds z=iz0 and z=min(iz0+1, GD-1) == clamped iz1. exact.

    float wx0 = 1.0f - tx, wx1 = tx;
    float wy0 = 1.0f - ty, wy1 = ty;
    float wz0 = 1.0f - tz, wz1 = tz;

    const uint4* p0 = ws + ((size_t)(ix0 * GD + iy0) * GD + iz0) * 4;
    const uint4* p1 = ws + ((size_t)(ix0 * GD + iy1) * GD + iz0) * 4;
    const uint4* p2 = ws + ((size_t)(ix1 * GD + iy0) * GD + iz0) * 4;
    const uint4* p3 = ws + ((size_t)(ix1 * GD + iy1) * GD + iz0) * 4;

    // batch ALL 16 line-loads up front: maximal MLP per wave
    uint4 q[16];
#pragma unroll
    for (int j = 0; j < 4; ++j) {
        q[0 + j]  = p0[j];
        q[4 + j]  = p1[j];
        q[8 + j]  = p2[j];
        q[12 + j] = p3[j];
    }

    float wxy[4] = { wx0 * wy0, wx0 * wy1, wx1 * wy0, wx1 * wy1 };

    float acc[NCH];
#pragma unroll
    for (int c = 0; c < NCH; ++c) acc[c] = 0.0f;

#pragma unroll
    for (int r = 0; r < 4; ++r) {
        unsigned u0[8] = { q[4 * r + 0].x, q[4 * r + 0].y, q[4 * r + 0].z, q[4 * r + 0].w,
                           q[4 * r + 1].x, q[4 * r + 1].y, q[4 * r + 1].z, q[4 * r + 1].w };
        unsigned u1[8] = { q[4 * r + 2].x, q[4 * r + 2].y, q[4 * r + 2].z, q[4 * r + 2].w,
                           q[4 * r + 3].x, q[4 * r + 3].y, q[4 * r + 3].z, q[4 * r + 3].w };
        float wxyr = wxy[r];
#pragma unroll
        for (int k = 0; k < 8; ++k) {
            float z0lo = __builtin_bit_cast(float, u0[k] << 16);
            float z0hi = __builtin_bit_cast(float, u0[k] & 0xffff0000u);
            float z1lo = __builtin_bit_cast(float, u1[k] << 16);
            float z1hi = __builtin_bit_cast(float, u1[k] & 0xffff0000u);
            acc[2 * k + 0] += wxyr * (wz0 * z0lo + wz1 * z1lo);
            acc[2 * k + 1] += wxyr * (wz0 * z0hi + wz1 * z1hi);
        }
    }

#pragma unroll
    for (int c = 0; c < NCH; ++c)
        __builtin_nontemporal_store(acc[c], out + (size_t)c * N + n);  // never re-read
}

// ---------- fallback: direct gather from native layout (fp32) ----------
__global__ __launch_bounds__(256) void interp_direct_k(const float* __restrict__ in,
                                                       const float* __restrict__ coords,
                                                       float* __restrict__ out, int N) {
    int n = blockIdx.x * 256 + threadIdx.x;
    if (n >= N) return;
    float cx = (coords[3 * n + 0] + 1.0f) * 0.5f * (float)(GD - 1);
    float cy = (coords[3 * n + 1] + 1.0f) * 0.5f * (float)(GD - 1);
    float cz = (coords[3 * n + 2] + 1.0f) * 0.5f * (float)(GD - 1);
    float fx = floorf(cx), fy = floorf(cy), fz = floorf(cz);
    float tx = cx - fx, ty = cy - fy, tz = cz - fz;
    int ix = (int)fx, iy = (int)fy, iz = (int)fz;
    int ix0 = min(max(ix, 0), GD - 1), ix1 = min(max(ix + 1, 0), GD - 1);
    int iy0 = min(max(iy, 0), GD - 1), iy1 = min(max(iy + 1, 0), GD - 1);
    int iz0 = min(max(iz, 0), GD - 1), iz1 = min(max(iz + 1, 0), GD - 1);
    float wx0 = 1.0f - tx, wx1 = tx, wy0 = 1.0f - ty, wy1 = ty, wz0 = 1.0f - tz, wz1 = tz;
    int o000 = (ix0 * GD + iy0) * GD + iz0, o001 = (ix0 * GD + iy0) * GD + iz1;
    int o010 = (ix0 * GD + iy1) * GD + iz0, o011 = (ix0 * GD + iy1) * GD + iz1;
    int o100 = (ix1 * GD + iy0) * GD + iz0, o101 = (ix1 * GD + iy0) * GD + iz1;
    int o110 = (ix1 * GD + iy1) * GD + iz0, o111 = (ix1 * GD + iy1) * GD + iz1;
    float w000 = wx0 * wy0 * wz0, w001 = wx0 * wy0 * wz1;
    float w010 = wx0 * wy1 * wz0, w011 = wx0 * wy1 * wz1;
    float w100 = wx1 * wy0 * wz0, w101 = wx1 * wy0 * wz1;
    float w110 = wx1 * wy1 * wz0, w111 = wx1 * wy1 * wz1;
#pragma unroll
    for (int c = 0; c < NCH; ++c) {
        const float* g = in + (size_t)c * VOX;
        float acc = w000 * g[o000] + w001 * g[o001] + w010 * g[o010] + w011 * g[o011]
                  + w100 * g[o100] + w101 * g[o101] + w110 * g[o110] + w111 * g[o111];
        out[(size_t)c * N + n] = acc;
    }
}

extern "C" void kernel_launch(void* const* d_in, const int* in_sizes, int n_in,
                              void* d_out, int out_size, void* d_ws, size_t ws_size,
                              hipStream_t stream) {
    const float* input  = (const float*)d_in[0];
    const float* coords = (const float*)d_in[1];
    float* out = (float*)d_out;
    int N = in_sizes[1] / 3;  // 1,000,000
    int nb = (N + 255) / 256;

    size_t need = (size_t)VOX * 64;  // 134,217,728 B pair layout
    if (ws_size >= need) {
        transpose_pair_b2_k<<<VOX / 2048, 256, 0, stream>>>(input, (uint4*)d_ws);
        interp_pair_k<<<nb, 256, 0, stream>>>((const uint4*)d_ws, coords, out, N);
    } else {
        interp_direct_k<<<nb, 256, 0, stream>>>(input, coords, out, N);
    }
}